// Round 7
// baseline (284.456 us; speedup 1.0000x reference)
//
#include <hip/hip_runtime.h>
#include <hip/hip_bf16.h>
#include <hip/hip_cooperative_groups.h>

namespace cg = cooperative_groups;

// B=2048, IN=1024, HID=512, FEAT=256, fp32 in/out.
//   h_b = relu(x_b @ W_feat + b_feat); f0 = h0 @ W_br0 + b_br0
//   Kron trick + fold: t = h1 @ Wc + bc, Wc = W_br1 @ Wr, bc = b_br1 @ Wr
//   out[b,c] = sum_i f0[b,i] * t[b, i*2+c] + b_out[c]
// R7: ONE cooperative kernel, 3 phases with grid.sync():
//   P1 pack (FS layout) -> P2 wave-GEMM {h0,h1,Wc} -> P3 tail (f0+t+kron).
// FS layout: chunk(mt,kt,lane) = X[mt*16+(lane&15)][kt*32+(lane>>4)*8 ..+7].

typedef __attribute__((ext_vector_type(8))) short bf16x8;
typedef __attribute__((ext_vector_type(4))) float f32x4;
typedef unsigned short u16;

__device__ __forceinline__ u16 f2bf(float f) {
    unsigned int u = __float_as_uint(f);
    return (u16)((u + 0x7FFFu + ((u >> 16) & 1u)) >> 16);   // RNE
}

__device__ __forceinline__ void fs_rm(const float* __restrict__ src,
                                      u16* __restrict__ dst, int lgK, int c) {
    const int lane = c & 63, t = c >> 6;
    const int kt = t & ((1 << (lgK - 5)) - 1);
    const int mt = t >> (lgK - 5);
    const int m = mt * 16 + (lane & 15);
    const int k = kt * 32 + (lane >> 4) * 8;
    const float* p = src + ((size_t)m << lgK) + k;
    float4 v0 = *(const float4*)p;
    float4 v1 = *(const float4*)(p + 4);
    ushort4 h0; h0.x = f2bf(v0.x); h0.y = f2bf(v0.y); h0.z = f2bf(v0.z); h0.w = f2bf(v0.w);
    ushort4 h1; h1.x = f2bf(v1.x); h1.y = f2bf(v1.y); h1.z = f2bf(v1.z); h1.w = f2bf(v1.w);
    *(ushort4*)&dst[(size_t)c * 8]     = h0;
    *(ushort4*)&dst[(size_t)c * 8 + 4] = h1;
}
__device__ __forceinline__ void fs_cm(const float* __restrict__ src,
                                      u16* __restrict__ dst, int N, int lgK, int c) {
    const int lane = c & 63, t = c >> 6;
    const int kt = t & ((1 << (lgK - 5)) - 1);
    const int mt = t >> (lgK - 5);
    const int n = mt * 16 + (lane & 15);
    const int k = kt * 32 + (lane >> 4) * 8;
    u16 b[8];
    #pragma unroll
    for (int j = 0; j < 8; ++j) b[j] = f2bf(src[(size_t)(k + j) * N + n]);
    *(ushort4*)&dst[(size_t)c * 8]     = *(ushort4*)&b[0];
    *(ushort4*)&dst[(size_t)c * 8 + 4] = *(ushort4*)&b[4];
}

#define MFMA4(A0_, A1_, B0_, B1_)                                              \
    acc00 = __builtin_amdgcn_mfma_f32_16x16x32_bf16(A0_, B0_, acc00, 0, 0, 0); \
    acc01 = __builtin_amdgcn_mfma_f32_16x16x32_bf16(A0_, B1_, acc01, 0, 0, 0); \
    acc10 = __builtin_amdgcn_mfma_f32_16x16x32_bf16(A1_, B0_, acc10, 0, 0, 0); \
    acc11 = __builtin_amdgcn_mfma_f32_16x16x32_bf16(A1_, B1_, acc11, 0, 0, 0);

// One wave = 32x32 output tile (2x2 frags of 16x16x32), 2-deep pipeline,
// FS bf16 output with out-K-dim 512 (K32o=16). K32 even, >= 2.
__device__ __forceinline__ void wave_gemm(
    const u16* __restrict__ A, const u16* __restrict__ B,
    const float* __restrict__ bias, u16* __restrict__ C,
    int K32, int tm, int tn, int lane, bool relu)
{
    const int lrow = lane & 15;
    const int quad = lane >> 4;

    const u16* pa0 = A + (((size_t)(2 * tm) * K32) * 64 + lane) * 8;
    const u16* pa1 = pa0 + (size_t)K32 * 512;
    const u16* pb0 = B + (((size_t)(2 * tn) * K32) * 64 + lane) * 8;
    const u16* pb1 = pb0 + (size_t)K32 * 512;

    f32x4 acc00 = {}, acc01 = {}, acc10 = {}, acc11 = {};
    bf16x8 A0[2], A1[2], B0[2], B1[2];

    A0[0] = *(const bf16x8*)pa0;
    A1[0] = *(const bf16x8*)pa1;
    B0[0] = *(const bf16x8*)pb0;
    B1[0] = *(const bf16x8*)pb1;
    A0[1] = *(const bf16x8*)(pa0 + 512);
    A1[1] = *(const bf16x8*)(pa1 + 512);
    B0[1] = *(const bf16x8*)(pb0 + 512);
    B1[1] = *(const bf16x8*)(pb1 + 512);

    int s = 0;
    for (; s + 2 < K32; s += 2) {
        MFMA4(A0[0], A1[0], B0[0], B1[0]);
        A0[0] = *(const bf16x8*)(pa0 + (size_t)(s + 2) * 512);
        A1[0] = *(const bf16x8*)(pa1 + (size_t)(s + 2) * 512);
        B0[0] = *(const bf16x8*)(pb0 + (size_t)(s + 2) * 512);
        B1[0] = *(const bf16x8*)(pb1 + (size_t)(s + 2) * 512);
        MFMA4(A0[1], A1[1], B0[1], B1[1]);
        A0[1] = *(const bf16x8*)(pa0 + (size_t)(s + 3) * 512);
        A1[1] = *(const bf16x8*)(pa1 + (size_t)(s + 3) * 512);
        B0[1] = *(const bf16x8*)(pb0 + (size_t)(s + 3) * 512);
        B1[1] = *(const bf16x8*)(pb1 + (size_t)(s + 3) * 512);
    }
    MFMA4(A0[0], A1[0], B0[0], B1[0]);
    MFMA4(A0[1], A1[1], B0[1], B1[1]);

    float bv[2] = {0.0f, 0.0f};
    if (bias) {
        bv[0] = bias[tn * 32 + lrow];
        bv[1] = bias[tn * 32 + 16 + lrow];
    }
    f32x4 acc[2][2] = {{acc00, acc01}, {acc10, acc11}};

    // FS out (out-K32o = 16). C/D layout: col=lane&15, row=quad*4+reg (m89/m91).
    #pragma unroll
    for (int fm = 0; fm < 2; ++fm)
        #pragma unroll
        for (int fn = 0; fn < 2; ++fn)
            #pragma unroll
            for (int reg = 0; reg < 4; ++reg) {
                const int m = tm * 32 + fm * 16 + quad * 4 + reg;
                const int k = tn * 32 + fn * 16 + lrow;
                float v = acc[fm][fn][reg] + bv[fn];
                if (relu) v = fmaxf(v, 0.0f);
                size_t a = (((size_t)(m >> 4) * 16 + (k >> 5)) * 64
                            + ((k >> 3) & 3) * 16 + (m & 15)) * 8 + (k & 7);
                C[a] = f2bf(v);
            }
}

struct Params {
    const float *x0, *x1, *W_feat, *b_feat, *W_br0, *b_br0,
                *W_br1, *b_br1, *W_out, *b_out;
    u16 *xb0, *xb1, *WfT, *Wb0T, *WrT, *Wb1c, *WcFS, *h0, *h1;
    float *bc;
    float *out;
};

// grid = 512 blocks x 256 threads (2 blocks/CU co-resident).
__global__ __launch_bounds__(256, 2) void mega(Params p)
{
    cg::grid_group grid = cg::this_grid();
    __shared__ float f0s[16 * 257];
    __shared__ float ts [16 * 513];

    const int tid  = threadIdx.x;
    const int gtid = blockIdx.x * 256 + tid;
    const int lane = tid & 63;
    const int wave = tid >> 6;

    // ---------- Phase 1: pack x + weights to FS bf16; bc ----------
    // flat ranges: xb0[0,262144) xb1[.,524288) WfT[.,589824) Wb0T[.,606208)
    //              WrT[.,622592) Wb1c[.,638976) bc[.,639488)
    for (int i = gtid; i < 639488; i += 512 * 256) {
        if (i < 262144)      fs_rm(p.x0, p.xb0, 10, i);
        else if (i < 524288) fs_rm(p.x1, p.xb1, 10, i - 262144);
        else if (i < 589824) fs_cm(p.W_feat, p.WfT, 512, 10, i - 524288);
        else if (i < 606208) fs_cm(p.W_br0, p.Wb0T, 256, 9, i - 589824);
        else if (i < 622592) fs_cm(p.W_out, p.WrT, 512, 8, i - 606208);
        else if (i < 638976) fs_rm(p.W_br1, p.Wb1c, 8, i - 622592);
        else {
            int n = i - 638976;          // bc[n] = sum_j b_br1[j]*Wr[j][n]
            float a = 0.0f;
            #pragma unroll 8
            for (int j = 0; j < 256; ++j) a += p.b_br1[j] * p.W_out[(size_t)j * 512 + n];
            p.bc[n] = a;
        }
    }
    grid.sync();

    // ---------- Phase 2: wave-GEMMs {h0, h1, Wc} ----------
    {
        const int wid = blockIdx.x * 4 + wave;       // 0..2047
        const int branch = wid >> 10;
        const int local = wid & 1023;
        const int tm = local >> 4, tn = local & 15;  // 64 x 16 tiles
        wave_gemm(branch ? p.xb1 : p.xb0, p.WfT, p.b_feat,
                  branch ? p.h1 : p.h0, 32, tm, tn, lane, true);
        if (wid < 256) {                             // Wc: 16 x 16 tiles, K32=8
            wave_gemm(p.WrT, p.Wb1c, nullptr, p.WcFS, 8,
                      wid >> 4, wid & 15, lane, false);
        }
    }
    grid.sync();

    // ---------- Phase 3: tail (f0 + t + kron) on blocks 0..127 ----------
    if (blockIdx.x < 128) {
        const int lrow = lane & 15, quad = lane >> 4;
        const int mt = blockIdx.x;                   // rows mt*16 .. +15

        const u16* A = (wave == 0) ? p.h0 : p.h1;
        bf16x8 a[16];
        #pragma unroll
        for (int k = 0; k < 16; ++k)
            a[k] = *(const bf16x8*)&A[(((size_t)mt * 16 + k) * 64 + lane) * 8];

        int fc0, nfc; const u16* Bp; const float* bias;
        if (wave == 0)      { fc0 = 0;  nfc = 16; Bp = p.Wb0T; bias = p.b_br0; }
        else if (wave == 1) { fc0 = 0;  nfc = 11; Bp = p.WcFS; bias = p.bc;   }
        else if (wave == 2) { fc0 = 11; nfc = 11; Bp = p.WcFS; bias = p.bc;   }
        else                { fc0 = 22; nfc = 10; Bp = p.WcFS; bias = p.bc;   }

        for (int l = 0; l < nfc; ++l) {
            const int fc = fc0 + l;
            f32x4 acc = {};
            #pragma unroll
            for (int k = 0; k < 16; ++k) {
                bf16x8 b = *(const bf16x8*)&Bp[(((size_t)fc * 16 + k) * 64 + lane) * 8];
                acc = __builtin_amdgcn_mfma_f32_16x16x32_bf16(a[k], b, acc, 0, 0, 0);
            }
            const int col = fc * 16 + lrow;
            const float bv = bias[col];
            if (wave == 0) {
                #pragma unroll
                for (int reg = 0; reg < 4; ++reg)
                    f0s[(quad * 4 + reg) * 257 + col] = acc[reg] + bv;
            } else {
                #pragma unroll
                for (int reg = 0; reg < 4; ++reg)
                    ts[(quad * 4 + reg) * 513 + col] = acc[reg] + bv;
            }
        }
        __syncthreads();

        const int r = tid >> 4, g = tid & 15;
        float p0 = 0.0f, p1 = 0.0f;
        #pragma unroll
        for (int j = 0; j < 16; ++j) {
            const int i = g * 16 + j;
            const float f = f0s[r * 257 + i];
            p0 += f * ts[r * 513 + 2 * i];
            p1 += f * ts[r * 513 + 2 * i + 1];
        }
        p0 += __shfl_down(p0, 8); p1 += __shfl_down(p1, 8);
        p0 += __shfl_down(p0, 4); p1 += __shfl_down(p1, 4);
        p0 += __shfl_down(p0, 2); p1 += __shfl_down(p1, 2);
        p0 += __shfl_down(p0, 1); p1 += __shfl_down(p1, 1);
        if (g == 0) {
            const int row = mt * 16 + r;
            p.out[(size_t)row * 2 + 0] = p0 + p.b_out[0];
            p.out[(size_t)row * 2 + 1] = p1 + p.b_out[1];
        }
    }
}

extern "C" void kernel_launch(void* const* d_in, const int* in_sizes, int n_in,
                              void* d_out, int out_size, void* d_ws, size_t ws_size,
                              hipStream_t stream) {
    Params p;
    p.x0     = (const float*)d_in[0];
    p.x1     = (const float*)d_in[1];
    p.W_feat = (const float*)d_in[2];
    p.b_feat = (const float*)d_in[3];
    p.W_br0  = (const float*)d_in[4];
    p.b_br0  = (const float*)d_in[5];
    p.W_br1  = (const float*)d_in[6];
    p.b_br1  = (const float*)d_in[7];
    p.W_out  = (const float*)d_in[8];
    p.b_out  = (const float*)d_in[9];
    p.out    = (float*)d_out;

    u16* ws = (u16*)d_ws;
    p.xb0  = ws;                     // FS 2048x1024
    p.xb1  = p.xb0  + 2097152;
    p.WfT  = p.xb1  + 2097152;       // FS-B 512x1024
    p.Wb0T = p.WfT  + 524288;        // FS-B 256x512
    p.WrT  = p.Wb0T + 131072;        // FS-A 512x256
    p.Wb1c = p.WrT  + 131072;        // FS-B 512x256
    p.WcFS = p.Wb1c + 131072;        // FS-B 512x512 (written in phase 2)
    p.h0   = p.WcFS + 262144;        // FS 2048x512
    p.h1   = p.h0   + 1048576;
    p.bc   = (float*)(p.h1 + 1048576);  // 512 fp32

    void* args[] = { (void*)&p };
    hipLaunchCooperativeKernel((const void*)mega, dim3(512), dim3(256),
                               args, 0, stream);
}

// Round 8
// 121.961 us; speedup vs baseline: 2.3324x; 2.3324x over previous
//
#include <hip/hip_runtime.h>
#include <hip/hip_bf16.h>

// B=2048, IN=1024, HID=512, FEAT=256, fp32 in/out.
//   h_b = relu(x_b @ W_feat + b_feat); f0 = h0 @ W_br0 + b_br0
//   Kron trick + fold: t = h1 @ Wc + bc, Wc = W_br1 @ Wr, bc = b_br1 @ Wr
//   out[b,c] = sum_i f0[b,i] * t[b, i*2+c] + b_out[c]
// R8: TLP-first. 16x32 wave tiles (1 A-chunk + 2 B-chunks + 2 MFMAs per
// 32-k step) -> 4608 waves in L1 (~18 waves/CU) vs R4's ~9. 4-wave blocks
// share one B-strip (L1-cache reuse). 4 launches: prep -> L1 -> G2 -> kron.
// FS layout: chunk(mt,kt,lane) = X[mt*16+(lane&15)][kt*32+(lane>>4)*8 ..+7].

typedef __attribute__((ext_vector_type(8))) short bf16x8;
typedef __attribute__((ext_vector_type(4))) float f32x4;
typedef unsigned short u16;

__device__ __forceinline__ u16 f2bf(float f) {
    unsigned int u = __float_as_uint(f);
    return (u16)((u + 0x7FFFu + ((u >> 16) & 1u)) >> 16);   // RNE
}
__device__ __forceinline__ float bf2f(u16 h) {
    return __uint_as_float(((unsigned int)h) << 16);
}

// ---- FS packers: one thread = one 16B chunk (8 bf16) ----
__device__ __forceinline__ void fs_rm(const float* __restrict__ src,
                                      u16* __restrict__ dst, int lgK, int c) {
    const int lane = c & 63, t = c >> 6;
    const int kt = t & ((1 << (lgK - 5)) - 1);
    const int mt = t >> (lgK - 5);
    const int m = mt * 16 + (lane & 15);
    const int k = kt * 32 + (lane >> 4) * 8;
    const float* p = src + ((size_t)m << lgK) + k;
    float4 v0 = *(const float4*)p;
    float4 v1 = *(const float4*)(p + 4);
    ushort4 h0; h0.x = f2bf(v0.x); h0.y = f2bf(v0.y); h0.z = f2bf(v0.z); h0.w = f2bf(v0.w);
    ushort4 h1; h1.x = f2bf(v1.x); h1.y = f2bf(v1.y); h1.z = f2bf(v1.z); h1.w = f2bf(v1.w);
    *(ushort4*)&dst[(size_t)c * 8]     = h0;
    *(ushort4*)&dst[(size_t)c * 8 + 4] = h1;
}
__device__ __forceinline__ void fs_cm(const float* __restrict__ src,
                                      u16* __restrict__ dst, int N, int lgK, int c) {
    const int lane = c & 63, t = c >> 6;
    const int kt = t & ((1 << (lgK - 5)) - 1);
    const int mt = t >> (lgK - 5);
    const int n = mt * 16 + (lane & 15);
    const int k = kt * 32 + (lane >> 4) * 8;
    u16 b[8];
    #pragma unroll
    for (int j = 0; j < 8; ++j) b[j] = f2bf(src[(size_t)(k + j) * N + n]);
    *(ushort4*)&dst[(size_t)c * 8]     = *(ushort4*)&b[0];
    *(ushort4*)&dst[(size_t)c * 8 + 4] = *(ushort4*)&b[4];
}

// prep block ranges: [0,1024) xb0 | [1024,2048) xb1 | [2048,2304) WfT |
// [2304,2368) Wb0T | [2368,2432) WrT | [2432,2496) Wb1c | [2496,2498) bc
__global__ __launch_bounds__(256) void prep(
    const float* __restrict__ x0, u16* __restrict__ xb0,
    const float* __restrict__ x1, u16* __restrict__ xb1,
    const float* __restrict__ W_feat, u16* __restrict__ WfT,
    const float* __restrict__ W_br0,  u16* __restrict__ Wb0T,
    const float* __restrict__ W_out,  u16* __restrict__ WrT,
    const float* __restrict__ W_br1,  u16* __restrict__ Wb1c,
    const float* __restrict__ b_br1,  float* __restrict__ bc)
{
    const int bx = blockIdx.x, tid = threadIdx.x;
    if (bx < 1024)      fs_rm(x0, xb0, 10, bx * 256 + tid);
    else if (bx < 2048) fs_rm(x1, xb1, 10, (bx - 1024) * 256 + tid);
    else if (bx < 2304) fs_cm(W_feat, WfT, 512, 10, (bx - 2048) * 256 + tid);
    else if (bx < 2368) fs_cm(W_br0, Wb0T, 256, 9, (bx - 2304) * 256 + tid);
    else if (bx < 2432) fs_cm(W_out, WrT, 512, 8, (bx - 2368) * 256 + tid);
    else if (bx < 2496) fs_rm(W_br1, Wb1c, 8, (bx - 2432) * 256 + tid);
    else {
        int n = (bx - 2496) * 256 + tid;
        float a = 0.0f;
        #pragma unroll 8
        for (int j = 0; j < 256; ++j) a += b_br1[j] * W_out[(size_t)j * 512 + n];
        bc[n] = a;
    }
}

// ---- barrier-free 16x32-per-wave GEMM ----
// One wave = 16x32 output tile (1x2 frags of 16x16x32). Per 32-k step:
// 1 A-load + 2 B-loads + 2 MFMAs. 4 waves of a block share the same B-strip
// (consecutive tm) -> B comes from L1 after first wave touches it.
// flags: 1=relu, 4=FS bf16 out (out-K32o=16), 2=rm bf16 out, 0=rm fp32 out.
struct GD {
    const u16* A; const u16* B; const float* bias; void* C;
    int K32; int tncnt; int N; int flags;
};

__global__ __launch_bounds__(256) void gemm16(GD d0, GD d1, GD d2, int s1, int s2)
{
    const int bx = blockIdx.x;
    GD d; int local;
    if (bx < s1)      { d = d0; local = bx; }
    else if (bx < s2) { d = d1; local = bx - s1; }
    else              { d = d2; local = bx - s2; }

    const int wave = threadIdx.x >> 6;
    const int lane = threadIdx.x & 63;
    const int lrow = lane & 15, quad = lane >> 4;
    const int tn = local % d.tncnt;
    const int tm = (local / d.tncnt) * 4 + wave;
    const int K32 = d.K32;              // 8, 16, or 32 (even)

    const u16* pa  = d.A + (((size_t)tm * K32) * 64 + lane) * 8;
    const u16* pb0 = d.B + (((size_t)(2 * tn) * K32) * 64 + lane) * 8;
    const u16* pb1 = pb0 + (size_t)K32 * 512;

    f32x4 acc0 = {}, acc1 = {};
    bf16x8 a[2], b0[2], b1[2];

    a[0]  = *(const bf16x8*)pa;
    b0[0] = *(const bf16x8*)pb0;
    b1[0] = *(const bf16x8*)pb1;
    a[1]  = *(const bf16x8*)(pa + 512);
    b0[1] = *(const bf16x8*)(pb0 + 512);
    b1[1] = *(const bf16x8*)(pb1 + 512);

    int s = 0;
    for (; s + 2 < K32; s += 2) {
        acc0 = __builtin_amdgcn_mfma_f32_16x16x32_bf16(a[0], b0[0], acc0, 0, 0, 0);
        acc1 = __builtin_amdgcn_mfma_f32_16x16x32_bf16(a[0], b1[0], acc1, 0, 0, 0);
        a[0]  = *(const bf16x8*)(pa  + (size_t)(s + 2) * 512);
        b0[0] = *(const bf16x8*)(pb0 + (size_t)(s + 2) * 512);
        b1[0] = *(const bf16x8*)(pb1 + (size_t)(s + 2) * 512);
        acc0 = __builtin_amdgcn_mfma_f32_16x16x32_bf16(a[1], b0[1], acc0, 0, 0, 0);
        acc1 = __builtin_amdgcn_mfma_f32_16x16x32_bf16(a[1], b1[1], acc1, 0, 0, 0);
        a[1]  = *(const bf16x8*)(pa  + (size_t)(s + 3) * 512);
        b0[1] = *(const bf16x8*)(pb0 + (size_t)(s + 3) * 512);
        b1[1] = *(const bf16x8*)(pb1 + (size_t)(s + 3) * 512);
    }
    acc0 = __builtin_amdgcn_mfma_f32_16x16x32_bf16(a[0], b0[0], acc0, 0, 0, 0);
    acc1 = __builtin_amdgcn_mfma_f32_16x16x32_bf16(a[0], b1[0], acc1, 0, 0, 0);
    acc0 = __builtin_amdgcn_mfma_f32_16x16x32_bf16(a[1], b0[1], acc0, 0, 0, 0);
    acc1 = __builtin_amdgcn_mfma_f32_16x16x32_bf16(a[1], b1[1], acc1, 0, 0, 0);

    float bv[2] = {0.0f, 0.0f};
    if (d.bias) {
        bv[0] = d.bias[tn * 32 + lrow];
        bv[1] = d.bias[tn * 32 + 16 + lrow];
    }
    f32x4 acc[2] = {acc0, acc1};

    // C/D layout: col=lane&15, row=quad*4+reg (verified m89/m91).
    if (d.flags & 4) {                  // FS bf16 out, out-K32o = 16
        u16* Co = (u16*)d.C;
        #pragma unroll
        for (int fn = 0; fn < 2; ++fn)
            #pragma unroll
            for (int reg = 0; reg < 4; ++reg) {
                const int m = tm * 16 + quad * 4 + reg;
                const int k = tn * 32 + fn * 16 + lrow;
                float v = acc[fn][reg] + bv[fn];
                if (d.flags & 1) v = fmaxf(v, 0.0f);
                size_t adr = (((size_t)(m >> 4) * 16 + (k >> 5)) * 64
                              + ((k >> 3) & 3) * 16 + (m & 15)) * 8 + (k & 7);
                Co[adr] = f2bf(v);
            }
    } else if (d.flags & 2) {           // row-major bf16 (f0)
        u16* Co = (u16*)d.C;
        #pragma unroll
        for (int fn = 0; fn < 2; ++fn)
            #pragma unroll
            for (int reg = 0; reg < 4; ++reg) {
                const int m = tm * 16 + quad * 4 + reg;
                const int n = tn * 32 + fn * 16 + lrow;
                float v = acc[fn][reg] + bv[fn];
                if (d.flags & 1) v = fmaxf(v, 0.0f);
                Co[(size_t)m * d.N + n] = f2bf(v);
            }
    } else {                            // row-major fp32 (t)
        float* Co = (float*)d.C;
        #pragma unroll
        for (int fn = 0; fn < 2; ++fn)
            #pragma unroll
            for (int reg = 0; reg < 4; ++reg) {
                const int m = tm * 16 + quad * 4 + reg;
                const int n = tn * 32 + fn * 16 + lrow;
                Co[(size_t)m * d.N + n] = acc[fn][reg] + bv[fn];
            }
    }
}

// out[b,c] = sum_i f0[b,i] * t[b, i*2+c] + b_out[c]; one block per row b.
__global__ __launch_bounds__(256) void kron_reduce(
    const u16* __restrict__ f0, const float* __restrict__ t,
    const float* __restrict__ b_out, float* __restrict__ out)
{
    const int b = blockIdx.x;
    const int i = threadIdx.x;
    const float  v  = bf2f(f0[(size_t)b * 256 + i]);
    const float2 tv = ((const float2*)(t + (size_t)b * 512))[i];
    float p0 = v * tv.x;
    float p1 = v * tv.y;
    #pragma unroll
    for (int off = 32; off > 0; off >>= 1) {
        p0 += __shfl_down(p0, off);
        p1 += __shfl_down(p1, off);
    }
    __shared__ float s0[4], s1[4];
    const int wv = i >> 6;
    if ((i & 63) == 0) { s0[wv] = p0; s1[wv] = p1; }
    __syncthreads();
    if (i == 0) {
        out[(size_t)b * 2 + 0] = s0[0] + s0[1] + s0[2] + s0[3] + b_out[0];
        out[(size_t)b * 2 + 1] = s1[0] + s1[1] + s1[2] + s1[3] + b_out[1];
    }
}

extern "C" void kernel_launch(void* const* d_in, const int* in_sizes, int n_in,
                              void* d_out, int out_size, void* d_ws, size_t ws_size,
                              hipStream_t stream) {
    const float* x0     = (const float*)d_in[0];
    const float* x1     = (const float*)d_in[1];
    const float* W_feat = (const float*)d_in[2];
    const float* b_feat = (const float*)d_in[3];
    const float* W_br0  = (const float*)d_in[4];
    const float* b_br0  = (const float*)d_in[5];
    const float* W_br1  = (const float*)d_in[6];
    const float* b_br1  = (const float*)d_in[7];
    const float* W_out  = (const float*)d_in[8];
    const float* b_out  = (const float*)d_in[9];
    float* out = (float*)d_out;

    u16* ws   = (u16*)d_ws;
    u16* xb0  = ws;                    // FS 2048x1024
    u16* xb1  = xb0  + 2097152;
    u16* WfT  = xb1  + 2097152;        // FS-B 512x1024
    u16* Wb0T = WfT  + 524288;         // FS-B 256x512
    u16* WrT  = Wb0T + 131072;         // FS-A 512x256
    u16* Wb1c = WrT  + 131072;         // FS-B 512x256
    u16* WcFS = Wb1c + 131072;         // FS-B 512x512 (written by L1)
    u16* h0   = WcFS + 262144;         // FS 2048x512
    u16* h1   = h0   + 1048576;
    u16* f0   = h1   + 1048576;        // rm bf16 2048x256
    float* t  = (float*)(f0 + 524288); // rm fp32 2048x512
    float* bc = t + 1048576;           // 512

    dim3 blk(256);

    // 1) prep (2498 blocks)
    prep<<<dim3(2498), blk, 0, stream>>>(
        x0, xb0, x1, xb1, W_feat, WfT, W_br0, Wb0T, W_out, WrT,
        W_br1, Wb1c, b_br1, bc);

    // 2) L1: h0, h1 (K32=32, relu, FS out) + WcFS (K32=8, FS out)
    //    blocks: 512 + 512 + 128 = 1152 (~4.5/CU, 18 waves/CU)
    GD g1a = { xb0, WfT,  b_feat,  h0,   32, 16, 512, 5 };
    GD g1b = { xb1, WfT,  b_feat,  h1,   32, 16, 512, 5 };
    GD g1c = { WrT, Wb1c, nullptr, WcFS,  8, 16, 512, 4 };
    gemm16<<<dim3(1152), blk, 0, stream>>>(g1a, g1b, g1c, 512, 1024);

    // 3) G2: f0 = h0 @ W_br0 + b_br0 (rm bf16) ; t = h1 @ Wc + bc (rm fp32)
    //    blocks: 256 + 512 = 768 (~3/CU)
    GD g2a = { h0, Wb0T, b_br0, f0, 16,  8, 256, 2 };
    GD g2b = { h1, WcFS, bc,    t,  16, 16, 512, 0 };
    gemm16<<<dim3(768), blk, 0, stream>>>(g2a, g2b, g2b, 256, 768);

    // 4) kron-reduce
    kron_reduce<<<dim3(2048), blk, 0, stream>>>(f0, t, b_out, out);
}